// Round 5
// baseline (266.953 us; speedup 1.0000x reference)
//
#include <hip/hip_runtime.h>
#include <math.h>

#define NVEC 32768   // 32*32*32 vectors
#define NE   1024    // codebook entries
#define ED   64      // embedding dim
#define TOT  2097152 // NVEC*ED total z elements
#define NCHUNK 8     // code chunks inside k_dist
#define CHUNK  128   // codes per chunk
#define MT     128   // vectors per k_dist block (R16: was 64)

// d_out offsets (in floats): loss | z_q_st | perplexity | min_encodings | idx
#define O_LOSS   0
#define O_ZQ     1
#define O_PERP   2097153
#define O_MINENC 2097154
#define O_IDX    35651586

// d_ws offsets (in floats)
#define W_PIDX   0        // [32768] final idx (int), written by k_dist
#define W_CS     32768    // [1024] int counts (atomic)
#define W_SUMENC 33792    // [1024*64] float (atomic)
#define W_NEWEMB 99328    // [1024*64]
#define W_ESQ    164864   // [1024] ||e||^2, exact np-pairwise

// R18 = R17 resubmitted verbatim after an infrastructure failure (container
// acquisition failed twice; no kernel verdict). R17 = R16 with the Stage-A
// trip-count bug fixed: 64c x 128m = 8192 FLOATS = 2048 float4 -> 8 iters,
// not 32 (R16 read z OOB and wrote 130KB into a 68KB LDS alloc).
// Design rationale: k_dist was LDS-read-BW bound (R1: VALU-active ~39us;
// 4m x 8k tile = 1.5 B/FMA). 8m x 8k tile = 1.0 B/FMA. s_a stores quads via
// perm(q) = (q>>1)|((q&1)<<4) so the 8m A-read is two conflict-free float4s
// (+4mi, +64+4mi). FMA order, esq/zsq trees, argmin merge bit-identical ->
// idx bit-identical. k_ema codebook update vectorized (float4 x16, unroll 4).

// blocks 0..64: zero cnt+sumenc (66560 floats = 16640 float4) + out[O_LOSS].
// blocks 65..68: esq[code] with the exact np-pairwise rounding.
__global__ void __launch_bounds__(256) k_pre(const float* __restrict__ emb,
                                             float* __restrict__ ws,
                                             float* __restrict__ out) {
    int b = blockIdx.x;
    if (b < 65) {
        int i = b * 256 + threadIdx.x;  // 0..16639, exactly 65*256
        float4 zv; zv.x = 0.f; zv.y = 0.f; zv.z = 0.f; zv.w = 0.f;
        *(float4*)(ws + W_CS + i * 4) = zv;
        if (b == 0 && threadIdx.x == 0) out[O_LOSS] = 0.f;
    } else {
        int code = (b - 65) * 256 + threadIdx.x;  // 4*256 = 1024
        const float* ep = emb + (size_t)code * ED;
        float r[8];
#pragma unroll
        for (int j = 0; j < 8; ++j) r[j] = __fmul_rn(ep[j], ep[j]);
#pragma unroll
        for (int i = 8; i < 64; i += 8)
#pragma unroll
            for (int j = 0; j < 8; ++j)
                r[j] = __fadd_rn(r[j], __fmul_rn(ep[i + j], ep[i + j]));
        ws[W_ESQ + code] = __fadd_rn(
            __fadd_rn(__fadd_rn(r[0], r[1]), __fadd_rn(r[2], r[3])),
            __fadd_rn(__fadd_rn(r[4], r[5]), __fadd_rn(r[6], r[7])));
    }
}

// phys float offset of logical m within an s_a row (perm'd quads)
__device__ __forceinline__ int apos(int m) {
    return ((m & 4) << 4) + ((m >> 3) << 2) + (m & 3);
}

__global__ void __launch_bounds__(256) k_dist(const float* __restrict__ z,
                                              const float* __restrict__ emb,
                                              const float* __restrict__ esq_g,
                                              int* __restrict__ fidx,
                                              int* __restrict__ cnt,
                                              float* __restrict__ sumenc,
                                              float* __restrict__ out) {
    __shared__ __align__(16) float s_a[64 * 128];   // [c][m-perm] : 2*z (32 KB)
    __shared__ __align__(16) float s_b[64 * 132];   // [c][k-swizzled] (33 KB)
    __shared__ float s_esq[CHUNK];
    __shared__ float s_zsq[MT];
    __shared__ int s_bi[MT];

    int tid = threadIdx.x;
    int n0 = blockIdx.x * MT;
    int b = n0 >> 10, hw0 = n0 & 1023;  // MT=128 tile never crosses b (1024/128=8)
    const float* zb = z + b * 65536 + hw0;

    // Stage A: 64c x 128m = 8192 floats = 2048 float4 / 256 thr = 8 each.
    // logical quad q = f4i & 31 (m = 4q..4q+3) -> phys f4 off ((q&1)<<6)+((q>>1)<<2)
#pragma unroll
    for (int j = 0; j < 8; ++j) {
        int f4i = j * 256 + tid;
        int q = f4i & 31, c = f4i >> 5;   // c in 0..63
        float4 v = *(const float4*)(zb + (c << 10) + q * 4);
        v.x = __fmul_rn(2.0f, v.x);
        v.y = __fmul_rn(2.0f, v.y);
        v.z = __fmul_rn(2.0f, v.z);
        v.w = __fmul_rn(2.0f, v.w);
        *(float4*)(s_a + c * 128 + ((q & 1) << 6) + ((q >> 1) << 2)) = v;
    }
    __syncthreads();

    // zsq (threads 0..127): np-pairwise over z; from (2z): exact x0.25.
    if (tid < MT) {
        int p = apos(tid);
        float r[8];
#pragma unroll
        for (int j = 0; j < 8; ++j) {
            float v = s_a[j * 128 + p];
            r[j] = __fmul_rn(v, v);
        }
#pragma unroll
        for (int i = 8; i < 64; i += 8)
#pragma unroll
            for (int j = 0; j < 8; ++j) {
                float v = s_a[(i + j) * 128 + p];
                r[j] = __fadd_rn(r[j], __fmul_rn(v, v));
            }
        s_zsq[tid] = __fmul_rn(0.25f, __fadd_rn(
            __fadd_rn(__fadd_rn(r[0], r[1]), __fadd_rn(r[2], r[3])),
            __fadd_rn(__fadd_rn(r[4], r[5]), __fadd_rn(r[6], r[7]))));
    }
    __syncthreads();

    int mi = tid & 15, ki = tid >> 4;   // 16 m-groups x 16 k-groups
    int kbase = ki * 8;
    float zs[8];
#pragma unroll
    for (int mu = 0; mu < 8; ++mu) zs[mu] = s_zsq[8 * mi + mu];

    float bd[8];
    int bix[8];
#pragma unroll
    for (int mu = 0; mu < 8; ++mu) { bd[mu] = 3.4e38f; bix[mu] = kbase; }

    for (int ch = 0; ch < NCHUNK; ++ch) {
        int k0 = ch * CHUNK;
        __syncthreads();  // previous chunk's readers of s_b/s_esq are done
        // Stage B transposed+swizzled (unchanged layout): phys quad (k4+c4)&31.
#pragma unroll
        for (int j = 0; j < 8; ++j) {
            int f4i = j * 256 + tid;
            int kl = f4i >> 4, c4 = f4i & 15;
            float4 v = *(const float4*)(emb + (size_t)(k0 + kl) * ED + c4 * 4);
            int base = (((kl >> 2) + c4) & 31) * 4 + (kl & 3);
            s_b[(c4 * 4 + 0) * 132 + base] = v.x;
            s_b[(c4 * 4 + 1) * 132 + base] = v.y;
            s_b[(c4 * 4 + 2) * 132 + base] = v.z;
            s_b[(c4 * 4 + 3) * 132 + base] = v.w;
        }
        if (tid < CHUNK) s_esq[tid] = esq_g[k0 + tid];
        __syncthreads();

        float acc[8][8];
#pragma unroll
        for (int mu = 0; mu < 8; ++mu)
#pragma unroll
            for (int ku = 0; ku < 8; ++ku) acc[mu][ku] = 0.f;

#pragma unroll 2
        for (int c = 0; c < 64; ++c) {
            int c4 = c >> 2;
            const float* ar = s_a + c * 128 + (mi << 2);
            float4 a0 = *(const float4*)(ar);        // m = 8mi..8mi+3
            float4 a1 = *(const float4*)(ar + 64);   // m = 8mi+4..8mi+7
            float4 b0 = *(const float4*)(s_b + c * 132 + ((2 * ki + c4) & 31) * 4);
            float4 b1 = *(const float4*)(s_b + c * 132 + ((2 * ki + 1 + c4) & 31) * 4);
#pragma unroll
            for (int mu = 0; mu < 8; ++mu) {
                float a = (mu < 4) ? (&a0.x)[mu] : (&a1.x)[mu - 4];
                acc[mu][0] = __fmaf_rn(a, b0.x, acc[mu][0]);
                acc[mu][1] = __fmaf_rn(a, b0.y, acc[mu][1]);
                acc[mu][2] = __fmaf_rn(a, b0.z, acc[mu][2]);
                acc[mu][3] = __fmaf_rn(a, b0.w, acc[mu][3]);
                acc[mu][4] = __fmaf_rn(a, b1.x, acc[mu][4]);
                acc[mu][5] = __fmaf_rn(a, b1.y, acc[mu][5]);
                acc[mu][6] = __fmaf_rn(a, b1.z, acc[mu][6]);
                acc[mu][7] = __fmaf_rn(a, b1.w, acc[mu][7]);
            }
        }

        // d = fl(fl(zsq+esq) - dot2); running per-thread argmin (k ascending)
#pragma unroll
        for (int mu = 0; mu < 8; ++mu)
#pragma unroll
            for (int ku = 0; ku < 8; ++ku) {
                float d = __fsub_rn(__fadd_rn(zs[mu], s_esq[kbase + ku]),
                                    acc[mu][ku]);
                if (d < bd[mu]) { bd[mu] = d; bix[mu] = k0 + kbase + ku; }
            }
    }

    // Merge 16 ki candidates per m, lexicographic (d, i) min == np.argmin.
    __syncthreads();
    float* red_d = s_b;               // [16][128]
    int* red_i = (int*)(s_b + 2048);  // [16][128]
#pragma unroll
    for (int mu = 0; mu < 8; ++mu) {
        red_d[ki * 128 + 8 * mi + mu] = bd[mu];
        red_i[ki * 128 + 8 * mi + mu] = bix[mu];
    }
    __syncthreads();
    if (tid < MT) {
        float best = red_d[tid];
        int bi = red_i[tid];
#pragma unroll
        for (int q = 1; q < 16; ++q) {
            float d = red_d[q * 128 + tid];
            int i = red_i[q * 128 + tid];
            if (d < best || (d == best && i < bi)) { best = d; bi = i; }
        }
        fidx[n0 + tid] = bi;
        out[O_IDX + n0 + tid] = (float)bi;
        s_bi[tid] = bi;
        atomicAdd(&cnt[bi], 1);  // int atomic: HW, exact
    }
    __syncthreads();  // merge done: s_b free again; s_bi visible

    // Transpose 0.5*z into s_b at stride 65 (m-major), 128x65 = 8320 <= 8448.
    // thread t: m = t&127, c = (t>>7)*32 + j. Reads 2-way, writes 2-way (free).
    {
        int m = tid & 127, half = tid >> 7;
        int p = apos(m);
#pragma unroll
        for (int j = 0; j < 32; ++j) {
            int c = half * 32 + j;
            s_b[m * 65 + c] = __fmul_rn(0.5f, s_a[c * 128 + p]);
        }
    }
    __syncthreads();

    // Coalesced scatter: wave w handles vectors m = 32w..32w+31. Lane = dim.
    // Each atomic instruction: sumenc[bi*64 + 0..63] = 256B contiguous.
    {
        int lane = tid & 63, w = tid >> 6;
#pragma unroll
        for (int t = 0; t < 32; ++t) {
            int m = (w << 5) | t;
            int bi = s_bi[m];
            float v = s_b[m * 65 + lane];
            unsafeAtomicAdd(sumenc + ((size_t)bi << 6) + lane, v);
        }
    }
}

// Single block, 1024 threads: EMA cluster-size + ntot/entropy reductions +
// perplexity + codebook update (float4 + unroll: latency-hidden).
__global__ void __launch_bounds__(1024) k_ema(const float* __restrict__ ema_cs,
                                              const float* __restrict__ ema_w,
                                              const int* __restrict__ cnt,
                                              const float* __restrict__ sumenc,
                                              float* __restrict__ newemb,
                                              float* __restrict__ out) {
    int k = threadIdx.x;  // 0..1023 == NE
    float c = (float)cnt[k];
    float ncs = 0.99f * ema_cs[k] + (1.0f - 0.99f) * c;
    float p = c * (1.0f / (float)NVEC);
    float e = p * logf(p + 1e-10f);
    float rn_ = ncs, re_ = e;
#pragma unroll
    for (int o = 32; o > 0; o >>= 1) {
        rn_ += __shfl_down(rn_, o, 64);
        re_ += __shfl_down(re_, o, 64);
    }
    __shared__ float sn[16], se_[16];
    __shared__ float s_n;
    int wave = k >> 6, lane = k & 63;
    if (lane == 0) { sn[wave] = rn_; se_[wave] = re_; }
    __syncthreads();
    if (k == 0) {
        float tn = 0.f, te = 0.f;
#pragma unroll
        for (int w = 0; w < 16; ++w) { tn += sn[w]; te += se_[w]; }
        s_n = tn;
        out[O_PERP] = expf(-te);
    }
    __syncthreads();
    float nt = s_n;
    float csn = (ncs + 1e-5f) / (nt + 1024.0f * 1e-5f) * nt;
    __shared__ float s_csn[NE];
    s_csn[k] = csn;
    __syncthreads();
    const float4* w4 = (const float4*)ema_w;
    const float4* s4 = (const float4*)sumenc;
    float4* n4 = (float4*)newemb;
#pragma unroll 4
    for (int it = 0; it < 16; ++it) {
        int t4 = it * 1024 + k;          // float4 index; row = t4>>4
        float4 w = w4[t4];
        float4 s = s4[t4];
        float cs_ = s_csn[t4 >> 4];
        float4 o;
        o.x = (0.99f * w.x + (1.0f - 0.99f) * s.x) / cs_;
        o.y = (0.99f * w.y + (1.0f - 0.99f) * s.y) / cs_;
        o.z = (0.99f * w.z + (1.0f - 0.99f) * s.z) / cs_;
        o.w = (0.99f * w.w + (1.0f - 0.99f) * s.w) / cs_;
        n4[t4] = o;
    }
}

// 2048 blocks x 256 threads: z_q + straight-through + loss + one-hot rows.
__global__ void __launch_bounds__(256) k_zq(const float* __restrict__ z,
                                            const int* __restrict__ idx,
                                            const float* __restrict__ newemb,
                                            float* __restrict__ out) {
    __shared__ int sbi[16];
    if (threadIdx.x < 16) sbi[threadIdx.x] = idx[blockIdx.x * 16 + threadIdx.x];
    __syncthreads();

    float local = 0.f;
#pragma unroll
    for (int i = 0; i < 4; ++i) {
        int t = blockIdx.x * 256 + threadIdx.x + i * 524288;
        int b = t >> 16, c = (t >> 10) & 63, hw = t & 1023;
        int n = (b << 10) | hw;
        float e = newemb[idx[n] * ED + c];
        float zv = z[t];
        float diff = e - zv;             // z_q - z
        out[O_ZQ + t] = zv + diff;       // straight-through: z + (z_q - z)
        local = fmaf(diff, diff, local);
    }

    // one-hot rows r0..r0+15
    int t = threadIdx.x;
    int r0 = blockIdx.x * 16;
    for (int r = 0; r < 16; ++r) {
        int rbi = sbi[r];
        float* rp = out + O_MINENC + (size_t)(r0 + r) * NE;
        if (t < 254) {
            int col = 2 + t * 4;
            float4 v;
            v.x = (col == rbi) ? 1.0f : 0.0f;
            v.y = (col + 1 == rbi) ? 1.0f : 0.0f;
            v.z = (col + 2 == rbi) ? 1.0f : 0.0f;
            v.w = (col + 3 == rbi) ? 1.0f : 0.0f;
            *(float4*)(rp + col) = v;
        } else if (t == 254) {
            float2 v;
            v.x = (0 == rbi) ? 1.0f : 0.0f;
            v.y = (1 == rbi) ? 1.0f : 0.0f;
            *(float2*)(rp) = v;
        } else {
            float4 v;
            v.x = (1018 == rbi) ? 1.0f : 0.0f;
            v.y = (1019 == rbi) ? 1.0f : 0.0f;
            v.z = (1020 == rbi) ? 1.0f : 0.0f;
            v.w = (1021 == rbi) ? 1.0f : 0.0f;
            *(float4*)(rp + 1018) = v;
            float2 w;
            w.x = (1022 == rbi) ? 1.0f : 0.0f;
            w.y = (1023 == rbi) ? 1.0f : 0.0f;
            *(float2*)(rp + 1022) = w;
        }
    }

#pragma unroll
    for (int o = 32; o > 0; o >>= 1) local += __shfl_down(local, o, 64);
    __shared__ float sp[4];
    int wave = threadIdx.x >> 6;
    if ((threadIdx.x & 63) == 0) sp[wave] = local;
    __syncthreads();
    if (threadIdx.x == 0)
        unsafeAtomicAdd(out + O_LOSS,
                        ((sp[0] + sp[1]) + (sp[2] + sp[3])) * (0.25f / (float)TOT));
}

extern "C" void kernel_launch(void* const* d_in, const int* in_sizes, int n_in,
                              void* d_out, int out_size, void* d_ws, size_t ws_size,
                              hipStream_t stream) {
    const float* z      = (const float*)d_in[0];
    const float* emb    = (const float*)d_in[1];
    const float* ema_cs = (const float*)d_in[2];
    const float* ema_w  = (const float*)d_in[3];
    float* out = (float*)d_out;
    float* ws  = (float*)d_ws;

    k_pre<<<69, 256, 0, stream>>>(emb, ws, out);
    k_dist<<<NVEC / MT, 256, 0, stream>>>(z, emb, ws + W_ESQ, (int*)(ws + W_PIDX),
                                          (int*)(ws + W_CS), ws + W_SUMENC, out);
    k_ema<<<1, 1024, 0, stream>>>(ema_cs, ema_w, (const int*)(ws + W_CS),
                                  ws + W_SUMENC, ws + W_NEWEMB, out);
    k_zq<<<2048, 256, 0, stream>>>(z, (const int*)(ws + W_PIDX), ws + W_NEWEMB,
                                   out);
}

// Round 6
// 258.551 us; speedup vs baseline: 1.0325x; 1.0325x over previous
//
#include <hip/hip_runtime.h>
#include <math.h>

#define NVEC 32768   // 32*32*32 vectors
#define NE   1024    // codebook entries
#define ED   64      // embedding dim
#define TOT  2097152 // NVEC*ED total z elements
#define NCHUNK 4     // code chunks inside k_dist (R19: was 8)
#define CHUNK  256   // codes per chunk (two 128-code subchunks)
#define MT     128   // vectors per k_dist block

// d_out offsets (in floats): loss | z_q_st | perplexity | min_encodings | idx
#define O_LOSS   0
#define O_ZQ     1
#define O_PERP   2097153
#define O_MINENC 2097154
#define O_IDX    35651586

// d_ws offsets (in floats)
#define W_PIDX   0        // [32768] final idx (int), written by k_dist
#define W_CS     32768    // [1024] int counts (atomic)
#define W_SUMENC 33792    // [1024*64] float (atomic)
#define W_NEWEMB 99328    // [1024*64]
#define W_ESQ    164864   // [1024] ||e||^2, exact np-pairwise

// R19 post-mortem of R18: MT=128 @ 256 threads -> grid 256 = 1 block/CU =
// 1 wave/SIMD (Occupancy 10.3%). VALUBusy 43% = the duty cycle of
// issue-8-ds_reads / stall-on-lgkmcnt / 64-FMA with nothing to overlap.
// Fix: 512 threads/block (8 waves/CU = 2/SIMD), keep the 8m x 8k tile
// (1.0 B/FMA). CHUNK=256 as TWO 128-code subchunks, each with the proven
// [c][k-swizzled] 132-float-row layout; thread ki 0..31, subchunk = ki>>4.
// FMA order over c, zsq/esq rounding, and lexicographic (d,i) merge (now 32
// candidates) identical -> idx bit-identical. LDS 100KB/block (1 block/CU).

// blocks 0..64: zero cnt+sumenc (66560 floats = 16640 float4) + out[O_LOSS].
// blocks 65..68: esq[code] with the exact np-pairwise rounding.
__global__ void __launch_bounds__(256) k_pre(const float* __restrict__ emb,
                                             float* __restrict__ ws,
                                             float* __restrict__ out) {
    int b = blockIdx.x;
    if (b < 65) {
        int i = b * 256 + threadIdx.x;  // 0..16639, exactly 65*256
        float4 zv; zv.x = 0.f; zv.y = 0.f; zv.z = 0.f; zv.w = 0.f;
        *(float4*)(ws + W_CS + i * 4) = zv;
        if (b == 0 && threadIdx.x == 0) out[O_LOSS] = 0.f;
    } else {
        int code = (b - 65) * 256 + threadIdx.x;  // 4*256 = 1024
        const float* ep = emb + (size_t)code * ED;
        float r[8];
#pragma unroll
        for (int j = 0; j < 8; ++j) r[j] = __fmul_rn(ep[j], ep[j]);
#pragma unroll
        for (int i = 8; i < 64; i += 8)
#pragma unroll
            for (int j = 0; j < 8; ++j)
                r[j] = __fadd_rn(r[j], __fmul_rn(ep[i + j], ep[i + j]));
        ws[W_ESQ + code] = __fadd_rn(
            __fadd_rn(__fadd_rn(r[0], r[1]), __fadd_rn(r[2], r[3])),
            __fadd_rn(__fadd_rn(r[4], r[5]), __fadd_rn(r[6], r[7])));
    }
}

// phys float offset of logical m within an s_a row (perm'd quads)
__device__ __forceinline__ int apos(int m) {
    return ((m & 4) << 4) + ((m >> 3) << 2) + (m & 3);
}

__global__ void __launch_bounds__(512) k_dist(const float* __restrict__ z,
                                              const float* __restrict__ emb,
                                              const float* __restrict__ esq_g,
                                              int* __restrict__ fidx,
                                              int* __restrict__ cnt,
                                              float* __restrict__ sumenc,
                                              float* __restrict__ out) {
    __shared__ __align__(16) float s_a[64 * 128];       // [c][m-perm] 2*z (32 KB)
    __shared__ __align__(16) float s_b[2 * 64 * 132];   // 2 subchunks (66 KB)
    __shared__ float s_esq[CHUNK];
    __shared__ float s_zsq[MT];
    __shared__ int s_bi[MT];

    int tid = threadIdx.x;
    int n0 = blockIdx.x * MT;
    int b = n0 >> 10, hw0 = n0 & 1023;  // MT=128 tile never crosses b
    const float* zb = z + b * 65536 + hw0;

    // Stage A: 64c x 128m = 2048 float4 / 512 thr = 4 each.
    // logical quad q -> phys f4 off ((q&1)<<6)+((q>>1)<<2); apos() inverts.
#pragma unroll
    for (int j = 0; j < 4; ++j) {
        int f4i = j * 512 + tid;
        int q = f4i & 31, c = f4i >> 5;   // c in 0..63
        float4 v = *(const float4*)(zb + (c << 10) + q * 4);
        v.x = __fmul_rn(2.0f, v.x);
        v.y = __fmul_rn(2.0f, v.y);
        v.z = __fmul_rn(2.0f, v.z);
        v.w = __fmul_rn(2.0f, v.w);
        *(float4*)(s_a + c * 128 + ((q & 1) << 6) + ((q >> 1) << 2)) = v;
    }
    __syncthreads();

    // zsq (threads 0..127): np-pairwise over z; from (2z): exact x0.25.
    if (tid < MT) {
        int p = apos(tid);
        float r[8];
#pragma unroll
        for (int j = 0; j < 8; ++j) {
            float v = s_a[j * 128 + p];
            r[j] = __fmul_rn(v, v);
        }
#pragma unroll
        for (int i = 8; i < 64; i += 8)
#pragma unroll
            for (int j = 0; j < 8; ++j) {
                float v = s_a[(i + j) * 128 + p];
                r[j] = __fadd_rn(r[j], __fmul_rn(v, v));
            }
        s_zsq[tid] = __fmul_rn(0.25f, __fadd_rn(
            __fadd_rn(__fadd_rn(r[0], r[1]), __fadd_rn(r[2], r[3])),
            __fadd_rn(__fadd_rn(r[4], r[5]), __fadd_rn(r[6], r[7]))));
    }
    __syncthreads();

    int mi = tid & 15, ki = tid >> 4;   // 16 m-groups x 32 k-groups
    int kbase = ki * 8;                 // 0..248 within the 256-chunk
    int kk = ki & 15;                   // k-group within subchunk
    const float* sbk = s_b + (ki >> 4) * 8448;  // subchunk base (wave-uniform)
    float zs[8];
#pragma unroll
    for (int mu = 0; mu < 8; ++mu) zs[mu] = s_zsq[8 * mi + mu];

    float bd[8];
    int bix[8];
#pragma unroll
    for (int mu = 0; mu < 8; ++mu) { bd[mu] = 3.4e38f; bix[mu] = kbase; }

    for (int ch = 0; ch < NCHUNK; ++ch) {
        int k0 = ch * CHUNK;
        __syncthreads();  // previous chunk's readers of s_b/s_esq are done
        // Stage B: 256 codes x 16 f4 = 4096 f4 / 512 thr = 8 each.
        // Subchunk sc = kl>>7; within: proven swizzle, phys quad (klr4+c4)&31.
#pragma unroll
        for (int j = 0; j < 8; ++j) {
            int f4i = j * 512 + tid;
            int kl = f4i >> 4, c4 = f4i & 15;   // kl 0..255
            float4 v = *(const float4*)(emb + (size_t)(k0 + kl) * ED + c4 * 4);
            int sc = kl >> 7, klr = kl & 127;
            float* sb = s_b + sc * 8448;
            int base = (((klr >> 2) + c4) & 31) * 4 + (klr & 3);
            sb[(c4 * 4 + 0) * 132 + base] = v.x;
            sb[(c4 * 4 + 1) * 132 + base] = v.y;
            sb[(c4 * 4 + 2) * 132 + base] = v.z;
            sb[(c4 * 4 + 3) * 132 + base] = v.w;
        }
        if (tid < CHUNK) s_esq[tid] = esq_g[k0 + tid];
        __syncthreads();

        float acc[8][8];
#pragma unroll
        for (int mu = 0; mu < 8; ++mu)
#pragma unroll
            for (int ku = 0; ku < 8; ++ku) acc[mu][ku] = 0.f;

#pragma unroll 2
        for (int c = 0; c < 64; ++c) {
            int c4 = c >> 2;
            const float* ar = s_a + c * 128 + (mi << 2);
            float4 a0 = *(const float4*)(ar);        // m = 8mi..8mi+3
            float4 a1 = *(const float4*)(ar + 64);   // m = 8mi+4..8mi+7
            float4 b0 = *(const float4*)(sbk + c * 132 + ((2 * kk + c4) & 31) * 4);
            float4 b1 = *(const float4*)(sbk + c * 132 + ((2 * kk + 1 + c4) & 31) * 4);
#pragma unroll
            for (int mu = 0; mu < 8; ++mu) {
                float a = (mu < 4) ? (&a0.x)[mu] : (&a1.x)[mu - 4];
                acc[mu][0] = __fmaf_rn(a, b0.x, acc[mu][0]);
                acc[mu][1] = __fmaf_rn(a, b0.y, acc[mu][1]);
                acc[mu][2] = __fmaf_rn(a, b0.z, acc[mu][2]);
                acc[mu][3] = __fmaf_rn(a, b0.w, acc[mu][3]);
                acc[mu][4] = __fmaf_rn(a, b1.x, acc[mu][4]);
                acc[mu][5] = __fmaf_rn(a, b1.y, acc[mu][5]);
                acc[mu][6] = __fmaf_rn(a, b1.z, acc[mu][6]);
                acc[mu][7] = __fmaf_rn(a, b1.w, acc[mu][7]);
            }
        }

        // d = fl(fl(zsq+esq) - dot2); running per-thread argmin (k ascending)
#pragma unroll
        for (int mu = 0; mu < 8; ++mu)
#pragma unroll
            for (int ku = 0; ku < 8; ++ku) {
                float d = __fsub_rn(__fadd_rn(zs[mu], s_esq[kbase + ku]),
                                    acc[mu][ku]);
                if (d < bd[mu]) { bd[mu] = d; bix[mu] = k0 + kbase + ku; }
            }
    }

    // Merge 32 ki candidates per m, lexicographic (d, i) min == np.argmin.
    __syncthreads();
    float* red_d = s_b;               // [32][128] = 4096 floats
    int* red_i = (int*)(s_b + 4096);  // [32][128]
#pragma unroll
    for (int mu = 0; mu < 8; ++mu) {
        red_d[ki * 128 + 8 * mi + mu] = bd[mu];
        red_i[ki * 128 + 8 * mi + mu] = bix[mu];
    }
    __syncthreads();
    if (tid < MT) {
        float best = red_d[tid];
        int bi = red_i[tid];
#pragma unroll
        for (int q = 1; q < 32; ++q) {
            float d = red_d[q * 128 + tid];
            int i = red_i[q * 128 + tid];
            if (d < best || (d == best && i < bi)) { best = d; bi = i; }
        }
        fidx[n0 + tid] = bi;
        out[O_IDX + n0 + tid] = (float)bi;
        s_bi[tid] = bi;
        atomicAdd(&cnt[bi], 1);  // int atomic: HW, exact
    }
    __syncthreads();  // merge consumed: s_b free again; s_bi visible

    // Transpose 0.5*z into s_b at stride 65 (m-major), 128x65 = 8320 floats.
    // thread t: m = t&127, quarter = t>>7 handles 16 c's. 2-way both sides.
    {
        int m = tid & 127, qt = tid >> 7;
        int p = apos(m);
#pragma unroll
        for (int j = 0; j < 16; ++j) {
            int c = qt * 16 + j;
            s_b[m * 65 + c] = __fmul_rn(0.5f, s_a[c * 128 + p]);
        }
    }
    __syncthreads();

    // Coalesced scatter: wave w handles vectors m = 16w..16w+15. Lane = dim.
    // Each atomic instruction: sumenc[bi*64 + 0..63] = 256B contiguous.
    {
        int lane = tid & 63, w = tid >> 6;   // 8 waves x 16 m
#pragma unroll
        for (int t = 0; t < 16; ++t) {
            int m = (w << 4) | t;
            int bi = s_bi[m];
            float v = s_b[m * 65 + lane];
            unsafeAtomicAdd(sumenc + ((size_t)bi << 6) + lane, v);
        }
    }
}

// Single block, 1024 threads: EMA cluster-size + ntot/entropy reductions +
// perplexity + codebook update (float4 + unroll: latency-hidden).
__global__ void __launch_bounds__(1024) k_ema(const float* __restrict__ ema_cs,
                                              const float* __restrict__ ema_w,
                                              const int* __restrict__ cnt,
                                              const float* __restrict__ sumenc,
                                              float* __restrict__ newemb,
                                              float* __restrict__ out) {
    int k = threadIdx.x;  // 0..1023 == NE
    float c = (float)cnt[k];
    float ncs = 0.99f * ema_cs[k] + (1.0f - 0.99f) * c;
    float p = c * (1.0f / (float)NVEC);
    float e = p * logf(p + 1e-10f);
    float rn_ = ncs, re_ = e;
#pragma unroll
    for (int o = 32; o > 0; o >>= 1) {
        rn_ += __shfl_down(rn_, o, 64);
        re_ += __shfl_down(re_, o, 64);
    }
    __shared__ float sn[16], se_[16];
    __shared__ float s_n;
    int wave = k >> 6, lane = k & 63;
    if (lane == 0) { sn[wave] = rn_; se_[wave] = re_; }
    __syncthreads();
    if (k == 0) {
        float tn = 0.f, te = 0.f;
#pragma unroll
        for (int w = 0; w < 16; ++w) { tn += sn[w]; te += se_[w]; }
        s_n = tn;
        out[O_PERP] = expf(-te);
    }
    __syncthreads();
    float nt = s_n;
    float csn = (ncs + 1e-5f) / (nt + 1024.0f * 1e-5f) * nt;
    __shared__ float s_csn[NE];
    s_csn[k] = csn;
    __syncthreads();
    const float4* w4 = (const float4*)ema_w;
    const float4* s4 = (const float4*)sumenc;
    float4* n4 = (float4*)newemb;
#pragma unroll 4
    for (int it = 0; it < 16; ++it) {
        int t4 = it * 1024 + k;          // float4 index; row = t4>>4
        float4 w = w4[t4];
        float4 s = s4[t4];
        float cs_ = s_csn[t4 >> 4];
        float4 o;
        o.x = (0.99f * w.x + (1.0f - 0.99f) * s.x) / cs_;
        o.y = (0.99f * w.y + (1.0f - 0.99f) * s.y) / cs_;
        o.z = (0.99f * w.z + (1.0f - 0.99f) * s.z) / cs_;
        o.w = (0.99f * w.w + (1.0f - 0.99f) * s.w) / cs_;
        n4[t4] = o;
    }
}

// 2048 blocks x 256 threads: z_q + straight-through + loss + one-hot rows.
__global__ void __launch_bounds__(256) k_zq(const float* __restrict__ z,
                                            const int* __restrict__ idx,
                                            const float* __restrict__ newemb,
                                            float* __restrict__ out) {
    __shared__ int sbi[16];
    if (threadIdx.x < 16) sbi[threadIdx.x] = idx[blockIdx.x * 16 + threadIdx.x];
    __syncthreads();

    float local = 0.f;
#pragma unroll
    for (int i = 0; i < 4; ++i) {
        int t = blockIdx.x * 256 + threadIdx.x + i * 524288;
        int b = t >> 16, c = (t >> 10) & 63, hw = t & 1023;
        int n = (b << 10) | hw;
        float e = newemb[idx[n] * ED + c];
        float zv = z[t];
        float diff = e - zv;             // z_q - z
        out[O_ZQ + t] = zv + diff;       // straight-through: z + (z_q - z)
        local = fmaf(diff, diff, local);
    }

    // one-hot rows r0..r0+15
    int t = threadIdx.x;
    int r0 = blockIdx.x * 16;
    for (int r = 0; r < 16; ++r) {
        int rbi = sbi[r];
        float* rp = out + O_MINENC + (size_t)(r0 + r) * NE;
        if (t < 254) {
            int col = 2 + t * 4;
            float4 v;
            v.x = (col == rbi) ? 1.0f : 0.0f;
            v.y = (col + 1 == rbi) ? 1.0f : 0.0f;
            v.z = (col + 2 == rbi) ? 1.0f : 0.0f;
            v.w = (col + 3 == rbi) ? 1.0f : 0.0f;
            *(float4*)(rp + col) = v;
        } else if (t == 254) {
            float2 v;
            v.x = (0 == rbi) ? 1.0f : 0.0f;
            v.y = (1 == rbi) ? 1.0f : 0.0f;
            *(float2*)(rp) = v;
        } else {
            float4 v;
            v.x = (1018 == rbi) ? 1.0f : 0.0f;
            v.y = (1019 == rbi) ? 1.0f : 0.0f;
            v.z = (1020 == rbi) ? 1.0f : 0.0f;
            v.w = (1021 == rbi) ? 1.0f : 0.0f;
            *(float4*)(rp + 1018) = v;
            float2 w;
            w.x = (1022 == rbi) ? 1.0f : 0.0f;
            w.y = (1023 == rbi) ? 1.0f : 0.0f;
            *(float2*)(rp + 1022) = w;
        }
    }

#pragma unroll
    for (int o = 32; o > 0; o >>= 1) local += __shfl_down(local, o, 64);
    __shared__ float sp[4];
    int wave = threadIdx.x >> 6;
    if ((threadIdx.x & 63) == 0) sp[wave] = local;
    __syncthreads();
    if (threadIdx.x == 0)
        unsafeAtomicAdd(out + O_LOSS,
                        ((sp[0] + sp[1]) + (sp[2] + sp[3])) * (0.25f / (float)TOT));
}

extern "C" void kernel_launch(void* const* d_in, const int* in_sizes, int n_in,
                              void* d_out, int out_size, void* d_ws, size_t ws_size,
                              hipStream_t stream) {
    const float* z      = (const float*)d_in[0];
    const float* emb    = (const float*)d_in[1];
    const float* ema_cs = (const float*)d_in[2];
    const float* ema_w  = (const float*)d_in[3];
    float* out = (float*)d_out;
    float* ws  = (float*)d_ws;

    k_pre<<<69, 256, 0, stream>>>(emb, ws, out);
    k_dist<<<NVEC / MT, 512, 0, stream>>>(z, emb, ws + W_ESQ, (int*)(ws + W_PIDX),
                                          (int*)(ws + W_CS), ws + W_SUMENC, out);
    k_ema<<<1, 1024, 0, stream>>>(ema_cs, ema_w, (const int*)(ws + W_CS),
                                  ws + W_SUMENC, ws + W_NEWEMB, out);
    k_zq<<<2048, 256, 0, stream>>>(z, (const int*)(ws + W_PIDX), ws + W_NEWEMB,
                                   out);
}

// Round 7
// 243.141 us; speedup vs baseline: 1.0979x; 1.0634x over previous
//
#include <hip/hip_runtime.h>
#include <math.h>

#define NVEC 32768   // 32*32*32 vectors
#define NE   1024    // codebook entries
#define ED   64      // embedding dim
#define TOT  2097152 // NVEC*ED total z elements
#define NCHUNK 4     // code chunks inside k_dist
#define CHUNK  256   // codes per chunk (two 128-code subchunks)
#define MT     128   // vectors per k_dist block

// d_out offsets (in floats): loss | z_q_st | perplexity | min_encodings | idx
#define O_LOSS   0
#define O_ZQ     1
#define O_PERP   2097153
#define O_MINENC 2097154
#define O_IDX    35651586

// d_ws offsets (in floats)
#define W_PIDX   0        // [32768] final idx (int), written by k_dist
#define W_CS     32768    // [1024] int counts (atomic)
#define W_SUMENC 33792    // [1024*64] float (atomic)
#define W_ESQ    164864   // [1024] ||e||^2, exact np-pairwise

// R20 post-mortem of R19: k_dist only 89.6 -> ~81us (falsified "occupancy
// alone"). Per-wave ds-latency stalls dominate: unroll-2 issues 8 ds_reads
// then waits ~120cyc; 2 barrier-locked waves/SIMD can't hide it. Fix 1:
// batch 4 c-iters of LDS loads into register arrays (16 float4 in flight),
// then 256 FMAs -> latency paid once per ~512 issue cycles. FMA order
// unchanged (c ascending) -> idx bit-identical. Fix 2: k_ema DELETED —
// newemb is not an output; k_zq computes csn[1024] redundantly per block
// (deterministic -> identical across blocks) and evaluates
// e = (0.99*ema_w[g] + (1-0.99)*sumenc[g]) / csn[idx] on the fly with the
// exact same fp expressions. Saves a single-block dispatch + gap + 512KB.

// blocks 0..64: zero cnt+sumenc (66560 floats = 16640 float4) + out[O_LOSS].
// blocks 65..68: esq[code] with the exact np-pairwise rounding.
__global__ void __launch_bounds__(256) k_pre(const float* __restrict__ emb,
                                             float* __restrict__ ws,
                                             float* __restrict__ out) {
    int b = blockIdx.x;
    if (b < 65) {
        int i = b * 256 + threadIdx.x;  // 0..16639, exactly 65*256
        float4 zv; zv.x = 0.f; zv.y = 0.f; zv.z = 0.f; zv.w = 0.f;
        *(float4*)(ws + W_CS + i * 4) = zv;
        if (b == 0 && threadIdx.x == 0) out[O_LOSS] = 0.f;
    } else {
        int code = (b - 65) * 256 + threadIdx.x;  // 4*256 = 1024
        const float* ep = emb + (size_t)code * ED;
        float r[8];
#pragma unroll
        for (int j = 0; j < 8; ++j) r[j] = __fmul_rn(ep[j], ep[j]);
#pragma unroll
        for (int i = 8; i < 64; i += 8)
#pragma unroll
            for (int j = 0; j < 8; ++j)
                r[j] = __fadd_rn(r[j], __fmul_rn(ep[i + j], ep[i + j]));
        ws[W_ESQ + code] = __fadd_rn(
            __fadd_rn(__fadd_rn(r[0], r[1]), __fadd_rn(r[2], r[3])),
            __fadd_rn(__fadd_rn(r[4], r[5]), __fadd_rn(r[6], r[7])));
    }
}

// phys float offset of logical m within an s_a row (perm'd quads)
__device__ __forceinline__ int apos(int m) {
    return ((m & 4) << 4) + ((m >> 3) << 2) + (m & 3);
}

__global__ void __launch_bounds__(512) k_dist(const float* __restrict__ z,
                                              const float* __restrict__ emb,
                                              const float* __restrict__ esq_g,
                                              int* __restrict__ fidx,
                                              int* __restrict__ cnt,
                                              float* __restrict__ sumenc,
                                              float* __restrict__ out) {
    __shared__ __align__(16) float s_a[64 * 128];       // [c][m-perm] 2*z (32 KB)
    __shared__ __align__(16) float s_b[2 * 64 * 132];   // 2 subchunks (66 KB)
    __shared__ float s_esq[CHUNK];
    __shared__ float s_zsq[MT];
    __shared__ int s_bi[MT];

    int tid = threadIdx.x;
    int n0 = blockIdx.x * MT;
    int b = n0 >> 10, hw0 = n0 & 1023;  // MT=128 tile never crosses b
    const float* zb = z + b * 65536 + hw0;

    // Stage A: 64c x 128m = 2048 float4 / 512 thr = 4 each.
#pragma unroll
    for (int j = 0; j < 4; ++j) {
        int f4i = j * 512 + tid;
        int q = f4i & 31, c = f4i >> 5;   // c in 0..63
        float4 v = *(const float4*)(zb + (c << 10) + q * 4);
        v.x = __fmul_rn(2.0f, v.x);
        v.y = __fmul_rn(2.0f, v.y);
        v.z = __fmul_rn(2.0f, v.z);
        v.w = __fmul_rn(2.0f, v.w);
        *(float4*)(s_a + c * 128 + ((q & 1) << 6) + ((q >> 1) << 2)) = v;
    }
    __syncthreads();

    // zsq (threads 0..127): np-pairwise over z; from (2z): exact x0.25.
    if (tid < MT) {
        int p = apos(tid);
        float r[8];
#pragma unroll
        for (int j = 0; j < 8; ++j) {
            float v = s_a[j * 128 + p];
            r[j] = __fmul_rn(v, v);
        }
#pragma unroll
        for (int i = 8; i < 64; i += 8)
#pragma unroll
            for (int j = 0; j < 8; ++j) {
                float v = s_a[(i + j) * 128 + p];
                r[j] = __fadd_rn(r[j], __fmul_rn(v, v));
            }
        s_zsq[tid] = __fmul_rn(0.25f, __fadd_rn(
            __fadd_rn(__fadd_rn(r[0], r[1]), __fadd_rn(r[2], r[3])),
            __fadd_rn(__fadd_rn(r[4], r[5]), __fadd_rn(r[6], r[7]))));
    }
    __syncthreads();

    int mi = tid & 15, ki = tid >> 4;   // 16 m-groups x 32 k-groups
    int kbase = ki * 8;                 // 0..248 within the 256-chunk
    int kk = ki & 15;                   // k-group within subchunk
    const float* sbk = s_b + (ki >> 4) * 8448;  // subchunk base (wave-uniform)
    float zs[8];
#pragma unroll
    for (int mu = 0; mu < 8; ++mu) zs[mu] = s_zsq[8 * mi + mu];

    float bd[8];
    int bix[8];
#pragma unroll
    for (int mu = 0; mu < 8; ++mu) { bd[mu] = 3.4e38f; bix[mu] = kbase; }

    for (int ch = 0; ch < NCHUNK; ++ch) {
        int k0 = ch * CHUNK;
        __syncthreads();  // previous chunk's readers of s_b/s_esq are done
        // Stage B: 256 codes x 16 f4 = 4096 f4 / 512 thr = 8 each.
#pragma unroll
        for (int j = 0; j < 8; ++j) {
            int f4i = j * 512 + tid;
            int kl = f4i >> 4, c4 = f4i & 15;   // kl 0..255
            float4 v = *(const float4*)(emb + (size_t)(k0 + kl) * ED + c4 * 4);
            int sc = kl >> 7, klr = kl & 127;
            float* sb = s_b + sc * 8448;
            int base = (((klr >> 2) + c4) & 31) * 4 + (klr & 3);
            sb[(c4 * 4 + 0) * 132 + base] = v.x;
            sb[(c4 * 4 + 1) * 132 + base] = v.y;
            sb[(c4 * 4 + 2) * 132 + base] = v.z;
            sb[(c4 * 4 + 3) * 132 + base] = v.w;
        }
        if (tid < CHUNK) s_esq[tid] = esq_g[k0 + tid];
        __syncthreads();

        float acc[8][8];
#pragma unroll
        for (int mu = 0; mu < 8; ++mu)
#pragma unroll
            for (int ku = 0; ku < 8; ++ku) acc[mu][ku] = 0.f;

        // R20: batch 4 c-iters of LDS loads (16 float4 in flight), then
        // 256 FMAs. FMA order identical to a straight c-loop (c ascending).
        for (int cg = 0; cg < 64; cg += 4) {
            float4 A0[4], A1[4], B0[4], B1[4];
#pragma unroll
            for (int j = 0; j < 4; ++j) {
                int c = cg + j;
                int c4 = c >> 2;
                const float* ar = s_a + c * 128 + (mi << 2);
                A0[j] = *(const float4*)(ar);        // m = 8mi..8mi+3
                A1[j] = *(const float4*)(ar + 64);   // m = 8mi+4..8mi+7
                B0[j] = *(const float4*)(sbk + c * 132 + ((2 * kk + c4) & 31) * 4);
                B1[j] = *(const float4*)(sbk + c * 132 + ((2 * kk + 1 + c4) & 31) * 4);
            }
#pragma unroll
            for (int j = 0; j < 4; ++j) {
#pragma unroll
                for (int mu = 0; mu < 8; ++mu) {
                    float a = (mu < 4) ? (&A0[j].x)[mu] : (&A1[j].x)[mu - 4];
                    acc[mu][0] = __fmaf_rn(a, B0[j].x, acc[mu][0]);
                    acc[mu][1] = __fmaf_rn(a, B0[j].y, acc[mu][1]);
                    acc[mu][2] = __fmaf_rn(a, B0[j].z, acc[mu][2]);
                    acc[mu][3] = __fmaf_rn(a, B0[j].w, acc[mu][3]);
                    acc[mu][4] = __fmaf_rn(a, B1[j].x, acc[mu][4]);
                    acc[mu][5] = __fmaf_rn(a, B1[j].y, acc[mu][5]);
                    acc[mu][6] = __fmaf_rn(a, B1[j].z, acc[mu][6]);
                    acc[mu][7] = __fmaf_rn(a, B1[j].w, acc[mu][7]);
                }
            }
        }

        // d = fl(fl(zsq+esq) - dot2); running per-thread argmin (k ascending)
#pragma unroll
        for (int mu = 0; mu < 8; ++mu)
#pragma unroll
            for (int ku = 0; ku < 8; ++ku) {
                float d = __fsub_rn(__fadd_rn(zs[mu], s_esq[kbase + ku]),
                                    acc[mu][ku]);
                if (d < bd[mu]) { bd[mu] = d; bix[mu] = k0 + kbase + ku; }
            }
    }

    // Merge 32 ki candidates per m, lexicographic (d, i) min == np.argmin.
    __syncthreads();
    float* red_d = s_b;               // [32][128] = 4096 floats
    int* red_i = (int*)(s_b + 4096);  // [32][128]
#pragma unroll
    for (int mu = 0; mu < 8; ++mu) {
        red_d[ki * 128 + 8 * mi + mu] = bd[mu];
        red_i[ki * 128 + 8 * mi + mu] = bix[mu];
    }
    __syncthreads();
    if (tid < MT) {
        float best = red_d[tid];
        int bi = red_i[tid];
#pragma unroll
        for (int q = 1; q < 32; ++q) {
            float d = red_d[q * 128 + tid];
            int i = red_i[q * 128 + tid];
            if (d < best || (d == best && i < bi)) { best = d; bi = i; }
        }
        fidx[n0 + tid] = bi;
        out[O_IDX + n0 + tid] = (float)bi;
        s_bi[tid] = bi;
        atomicAdd(&cnt[bi], 1);  // int atomic: HW, exact
    }
    __syncthreads();  // merge consumed: s_b free again; s_bi visible

    // Transpose 0.5*z into s_b at stride 65 (m-major), 128x65 = 8320 floats.
    {
        int m = tid & 127, qt = tid >> 7;
        int p = apos(m);
#pragma unroll
        for (int j = 0; j < 16; ++j) {
            int c = qt * 16 + j;
            s_b[m * 65 + c] = __fmul_rn(0.5f, s_a[c * 128 + p]);
        }
    }
    __syncthreads();

    // Coalesced scatter: wave w handles vectors m = 16w..16w+15. Lane = dim.
    {
        int lane = tid & 63, w = tid >> 6;   // 8 waves x 16 m
#pragma unroll
        for (int t = 0; t < 16; ++t) {
            int m = (w << 4) | t;
            int bi = s_bi[m];
            float v = s_b[m * 65 + lane];
            unsafeAtomicAdd(sumenc + ((size_t)bi << 6) + lane, v);
        }
    }
}

// 2048 blocks x 256 threads: csn (redundant per block, deterministic) +
// perplexity (block 0) + z_q + straight-through + loss + one-hot rows.
// e computed on the fly: (0.99*ema_w[g] + (1-0.99)*sumenc[g]) / csn[idx]
// — identical fp expressions to the old k_ema, so z_q is bit-identical.
__global__ void __launch_bounds__(256) k_zq(const float* __restrict__ z,
                                            const int* __restrict__ idx,
                                            const float* __restrict__ ema_cs,
                                            const float* __restrict__ ema_w,
                                            const int* __restrict__ cnt,
                                            const float* __restrict__ sumenc,
                                            float* __restrict__ out) {
    __shared__ float s_csn[NE];
    __shared__ float swn[4], swe[4];
    __shared__ int sbi[16];
    int tid = threadIdx.x;

    float myncs[4];
    float rn = 0.f, re = 0.f;
#pragma unroll
    for (int j = 0; j < 4; ++j) {
        int k = j * 256 + tid;
        float c = (float)cnt[k];
        float ncs = 0.99f * ema_cs[k] + (1.0f - 0.99f) * c;
        myncs[j] = ncs;
        rn += ncs;
        float p = c * (1.0f / (float)NVEC);
        re += p * logf(p + 1e-10f);
    }
#pragma unroll
    for (int o = 32; o > 0; o >>= 1) {
        rn += __shfl_down(rn, o, 64);
        re += __shfl_down(re, o, 64);
    }
    int wave = tid >> 6;
    if ((tid & 63) == 0) { swn[wave] = rn; swe[wave] = re; }
    if (tid < 16) sbi[tid] = idx[blockIdx.x * 16 + tid];
    __syncthreads();
    float nt = (swn[0] + swn[1]) + (swn[2] + swn[3]);
    if (blockIdx.x == 0 && tid == 0) {
        float te = (swe[0] + swe[1]) + (swe[2] + swe[3]);
        out[O_PERP] = expf(-te);
    }
#pragma unroll
    for (int j = 0; j < 4; ++j) {
        int k = j * 256 + tid;
        s_csn[k] = (myncs[j] + 1e-5f) / (nt + 1024.0f * 1e-5f) * nt;
    }
    __syncthreads();

    float local = 0.f;
#pragma unroll
    for (int i = 0; i < 4; ++i) {
        int t = blockIdx.x * 256 + tid + i * 524288;
        int b = t >> 16, c = (t >> 10) & 63, hw = t & 1023;
        int n = (b << 10) | hw;
        int g = idx[n] * ED + c;
        float nw = 0.99f * ema_w[g] + (1.0f - 0.99f) * sumenc[g];
        float e = nw / s_csn[g >> 6];
        float zv = z[t];
        float diff = e - zv;             // z_q - z
        out[O_ZQ + t] = zv + diff;       // straight-through: z + (z_q - z)
        local = fmaf(diff, diff, local);
    }

    // one-hot rows r0..r0+15
    int t = tid;
    int r0 = blockIdx.x * 16;
    for (int r = 0; r < 16; ++r) {
        int rbi = sbi[r];
        float* rp = out + O_MINENC + (size_t)(r0 + r) * NE;
        if (t < 254) {
            int col = 2 + t * 4;
            float4 v;
            v.x = (col == rbi) ? 1.0f : 0.0f;
            v.y = (col + 1 == rbi) ? 1.0f : 0.0f;
            v.z = (col + 2 == rbi) ? 1.0f : 0.0f;
            v.w = (col + 3 == rbi) ? 1.0f : 0.0f;
            *(float4*)(rp + col) = v;
        } else if (t == 254) {
            float2 v;
            v.x = (0 == rbi) ? 1.0f : 0.0f;
            v.y = (1 == rbi) ? 1.0f : 0.0f;
            *(float2*)(rp) = v;
        } else {
            float4 v;
            v.x = (1018 == rbi) ? 1.0f : 0.0f;
            v.y = (1019 == rbi) ? 1.0f : 0.0f;
            v.z = (1020 == rbi) ? 1.0f : 0.0f;
            v.w = (1021 == rbi) ? 1.0f : 0.0f;
            *(float4*)(rp + 1018) = v;
            float2 w;
            w.x = (1022 == rbi) ? 1.0f : 0.0f;
            w.y = (1023 == rbi) ? 1.0f : 0.0f;
            *(float2*)(rp + 1022) = w;
        }
    }

#pragma unroll
    for (int o = 32; o > 0; o >>= 1) local += __shfl_down(local, o, 64);
    __shared__ float sp[4];
    if ((tid & 63) == 0) sp[wave] = local;
    __syncthreads();
    if (tid == 0)
        unsafeAtomicAdd(out + O_LOSS,
                        ((sp[0] + sp[1]) + (sp[2] + sp[3])) * (0.25f / (float)TOT));
}

extern "C" void kernel_launch(void* const* d_in, const int* in_sizes, int n_in,
                              void* d_out, int out_size, void* d_ws, size_t ws_size,
                              hipStream_t stream) {
    const float* z      = (const float*)d_in[0];
    const float* emb    = (const float*)d_in[1];
    const float* ema_cs = (const float*)d_in[2];
    const float* ema_w  = (const float*)d_in[3];
    float* out = (float*)d_out;
    float* ws  = (float*)d_ws;

    k_pre<<<69, 256, 0, stream>>>(emb, ws, out);
    k_dist<<<NVEC / MT, 512, 0, stream>>>(z, emb, ws + W_ESQ, (int*)(ws + W_PIDX),
                                          (int*)(ws + W_CS), ws + W_SUMENC, out);
    k_zq<<<2048, 256, 0, stream>>>(z, (const int*)(ws + W_PIDX), ema_cs, ema_w,
                                   (const int*)(ws + W_CS), ws + W_SUMENC, out);
}